// Round 2
// baseline (920.233 us; speedup 1.0000x reference)
//
#include <hip/hip_runtime.h>
#include <stdint.h>

#define N_NODES   100000
#define N_EDGES   3200000
#define N_FEAT    512
#define HIDDEN    64
#define N_CLASSES 40

#define SCB  1024                    // scan block size
#define NBLK 98                      // ceil(100000/1024)

// ---------------- bf16 helpers (RNE) ----------------------------------------
__device__ __forceinline__ float bf2f(uint16_t u) {
  return __uint_as_float((uint32_t)u << 16);
}
__device__ __forceinline__ uint16_t f2bf(float f) {
  uint32_t x = __float_as_uint(f);
  return (uint16_t)((x + 0x7fffu + ((x >> 16) & 1u)) >> 16);
}

// ---------------- threefry2x32 (exact JAX semantics, key = (0,42)) ----------
__device__ __forceinline__ uint32_t rotl32(uint32_t x, uint32_t r) {
  return (x << r) | (x >> (32u - r));
}

__device__ __forceinline__ void threefry2x32(uint32_t k0, uint32_t k1,
                                             uint32_t x0, uint32_t x1,
                                             uint32_t& o0, uint32_t& o1) {
  uint32_t ks2 = k0 ^ k1 ^ 0x1BD11BDAu;
  x0 += k0; x1 += k1;
#define TF_R4(a,b,c,d) \
  x0 += x1; x1 = rotl32(x1,a); x1 ^= x0; \
  x0 += x1; x1 = rotl32(x1,b); x1 ^= x0; \
  x0 += x1; x1 = rotl32(x1,c); x1 ^= x0; \
  x0 += x1; x1 = rotl32(x1,d); x1 ^= x0;
  TF_R4(13,15,26,6)   x0 += k1;  x1 += ks2 + 1u;
  TF_R4(17,29,16,24)  x0 += ks2; x1 += k0  + 2u;
  TF_R4(13,15,26,6)   x0 += k0;  x1 += k1  + 3u;
  TF_R4(17,29,16,24)  x0 += k1;  x1 += ks2 + 4u;
  TF_R4(13,15,26,6)   x0 += ks2; x1 += k0  + 5u;
#undef TF_R4
  o0 = x0; o1 = x1;
}

// ---------------- CSR build: 1 int atomic per edge, L2-resident --------------
// (The old bucket/bin path avoided global atomics entirely but spent ~150+ us
//  on LDS histograms/scans/binary-search with a 196-block bottleneck kernel.
//  deg[]/cur[] are 400 KB — L2-resident; 3.2M int atomics are cheap.)
__global__ __launch_bounds__(256) void zero_kernel(int* __restrict__ deg) {
  int i = blockIdx.x * 256 + threadIdx.x;
  if (i < N_NODES) deg[i] = 0;
}

__global__ __launch_bounds__(256) void deg_kernel(const int* __restrict__ edges,
                                                  int* __restrict__ deg) {
  int i = blockIdx.x * 256 + threadIdx.x;           // i over E/4 (exact fit)
  const int4 d4 = reinterpret_cast<const int4*>(edges + N_EDGES)[i];
  atomicAdd(&deg[d4.x], 1);
  atomicAdd(&deg[d4.y], 1);
  atomicAdd(&deg[d4.z], 1);
  atomicAdd(&deg[d4.w], 1);
}

// scan1: per-block inclusive scan of deg -> block-exclusive into rowstart,
// block totals to bsum; also emits dinv = rsqrt(deg+1) (+1 self-loop).
__global__ __launch_bounds__(SCB) void scan1_kernel(const int* __restrict__ deg,
                                                    int* __restrict__ rowstart,
                                                    int* __restrict__ bsum,
                                                    float* __restrict__ dinv) {
  __shared__ int s[SCB];
  int t = threadIdx.x, b = blockIdx.x;
  int i = b * SCB + t;
  int v = (i < N_NODES) ? deg[i] : 0;
  s[t] = v;
  __syncthreads();
  for (int off = 1; off < SCB; off <<= 1) {
    int a = (t >= off) ? s[t - off] : 0;
    __syncthreads();
    s[t] += a;
    __syncthreads();
  }
  if (i < N_NODES) {
    rowstart[i] = s[t] - v;                         // block-local exclusive
    dinv[i] = rsqrtf((float)(v + 1));
  }
  if (t == SCB - 1) bsum[b] = s[t];
}

__global__ void scan2_kernel(int* __restrict__ bsum) {
  __shared__ int s[128];
  int t = threadIdx.x;
  int v = (t < NBLK) ? bsum[t] : 0;
  s[t] = v;
  __syncthreads();
  for (int off = 1; off < 128; off <<= 1) {
    int a = (t >= off) ? s[t - off] : 0;
    __syncthreads();
    s[t] += a;
    __syncthreads();
  }
  if (t < NBLK) bsum[t] = s[t] - v;                 // exclusive block offsets
}

__global__ __launch_bounds__(SCB) void scan3_kernel(int* __restrict__ rowstart,
                                                    const int* __restrict__ bsum,
                                                    int* __restrict__ cur) {
  int t = threadIdx.x, b = blockIdx.x;
  int i = b * SCB + t;
  if (i < N_NODES) {
    int r = rowstart[i] + bsum[b];
    rowstart[i] = r;
    cur[i] = r;
  }
  if (i == 0) rowstart[N_NODES] = N_EDGES;
}

__global__ __launch_bounds__(256) void scatter_kernel(const int* __restrict__ edges,
                                                      int* __restrict__ cur,
                                                      int* __restrict__ srcs) {
  int i = blockIdx.x * 256 + threadIdx.x;           // i over E/4 (exact fit)
  const int4 s4 = reinterpret_cast<const int4*>(edges)[i];
  const int4 d4 = reinterpret_cast<const int4*>(edges + N_EDGES)[i];
  int p0 = atomicAdd(&cur[d4.x], 1); srcs[p0] = s4.x;
  int p1 = atomicAdd(&cur[d4.y], 1); srcs[p1] = s4.y;
  int p2 = atomicAdd(&cur[d4.z], 1); srcs[p2] = s4.z;
  int p3 = atomicAdd(&cur[d4.w], 1); srcs[p3] = s4.w;
}

// ---------------- W1 prep: split-transpose to bf16 hi/lo --------------------
__global__ __launch_bounds__(256) void wprep_kernel(const float* __restrict__ W1,
                                                    uint16_t* __restrict__ Wth,
                                                    uint16_t* __restrict__ Wtl) {
  int id = blockIdx.x * 256 + threadIdx.x;          // 64*512 = 32768 total
  int col = id >> 9, k = id & 511;
  float v = W1[(size_t)k * HIDDEN + col];
  uint32_t u = __float_as_uint(v);
  uint32_t hb = u & 0xffff0000u;                    // truncated bf16 hi
  float lo = v - __uint_as_float(hb);               // exact residual
  Wth[id] = (uint16_t)(u >> 16);
  Wtl[id] = (uint16_t)(__float_as_uint(lo) >> 16);
}

// ---------------- GEMM1: hs1 = bf16((x @ W1) * dinv[n]) via bf16x3 MFMA -----
typedef __bf16 bf16x8 __attribute__((ext_vector_type(8)));
typedef float  f32x4  __attribute__((ext_vector_type(4)));

#define APAD 72   // LDS row stride in bf16 elems (144 B -> 2-way = free on b128)

__global__ __launch_bounds__(256, 2) void gemm1_kernel(
    const float* __restrict__ x, const uint16_t* __restrict__ Wth,
    const uint16_t* __restrict__ Wtl, const float* __restrict__ dinv,
    uint16_t* __restrict__ hs1) {
  __shared__ __align__(16) uint16_t Ah[128 * APAD];
  __shared__ __align__(16) uint16_t Al[128 * APAD];
  __shared__ __align__(16) uint16_t Bh[64 * APAD];
  __shared__ __align__(16) uint16_t Bl[64 * APAD];

  int t = threadIdx.x;
  int node0 = blockIdx.x * 128;
  int w = t >> 6, l = t & 63;
  int l15 = l & 15, l4 = l >> 4;

  f32x4 acc[2][4];
#pragma unroll
  for (int r = 0; r < 2; r++)
#pragma unroll
    for (int c = 0; c < 4; c++) acc[r][c] = (f32x4){0.f, 0.f, 0.f, 0.f};

  int an = t >> 4;            // node-sub per A pass (0..15)
  int ak = (t & 15) * 4;      // k0 within chunk for A staging
  int bc = t >> 3;            // col-sub per B pass (0..31)
  int bk = (t & 7) * 8;       // k0 within chunk for B staging

  for (int kc = 0; kc < N_FEAT; kc += 64) {
#pragma unroll
    for (int p = 0; p < 2; ++p) {
      int col = p * 32 + bc;
      *reinterpret_cast<uint4*>(&Bh[col * APAD + bk]) =
          *reinterpret_cast<const uint4*>(&Wth[(size_t)col * N_FEAT + kc + bk]);
      *reinterpret_cast<uint4*>(&Bl[col * APAD + bk]) =
          *reinterpret_cast<const uint4*>(&Wtl[(size_t)col * N_FEAT + kc + bk]);
    }
#pragma unroll
    for (int p = 0; p < 8; ++p) {
      int nl = p * 16 + an;
      int gr = node0 + nl; if (gr > N_NODES - 1) gr = N_NODES - 1;
      const float4 v = *reinterpret_cast<const float4*>(&x[(size_t)gr * N_FEAT + kc + ak]);
      uint32_t u0 = __float_as_uint(v.x), u1 = __float_as_uint(v.y);
      uint32_t u2 = __float_as_uint(v.z), u3 = __float_as_uint(v.w);
      float f0 = v.x - __uint_as_float(u0 & 0xffff0000u);
      float f1 = v.y - __uint_as_float(u1 & 0xffff0000u);
      float f2 = v.z - __uint_as_float(u2 & 0xffff0000u);
      float f3 = v.w - __uint_as_float(u3 & 0xffff0000u);
      uint32_t hi01 = (u0 >> 16) | (u1 & 0xffff0000u);
      uint32_t hi23 = (u2 >> 16) | (u3 & 0xffff0000u);
      uint32_t lo01 = (__float_as_uint(f0) >> 16) | (__float_as_uint(f1) & 0xffff0000u);
      uint32_t lo23 = (__float_as_uint(f2) >> 16) | (__float_as_uint(f3) & 0xffff0000u);
      *reinterpret_cast<uint2*>(&Ah[nl * APAD + ak]) = make_uint2(hi01, hi23);
      *reinterpret_cast<uint2*>(&Al[nl * APAD + ak]) = make_uint2(lo01, lo23);
    }
    __syncthreads();
#pragma unroll
    for (int s = 0; s < 2; ++s) {
      int ko = s * 32 + l4 * 8;
      bf16x8 a_h[2], a_l[2], b_h[4], b_l[4];
#pragma unroll
      for (int r = 0; r < 2; ++r) {
        int row = w * 32 + r * 16 + l15;
        a_h[r] = *reinterpret_cast<const bf16x8*>(&Ah[row * APAD + ko]);
        a_l[r] = *reinterpret_cast<const bf16x8*>(&Al[row * APAD + ko]);
      }
#pragma unroll
      for (int c = 0; c < 4; ++c) {
        int col = c * 16 + l15;
        b_h[c] = *reinterpret_cast<const bf16x8*>(&Bh[col * APAD + ko]);
        b_l[c] = *reinterpret_cast<const bf16x8*>(&Bl[col * APAD + ko]);
      }
#pragma unroll
      for (int r = 0; r < 2; ++r)
#pragma unroll
        for (int c = 0; c < 4; ++c) {
          acc[r][c] = __builtin_amdgcn_mfma_f32_16x16x32_bf16(a_h[r], b_h[c], acc[r][c], 0, 0, 0);
          acc[r][c] = __builtin_amdgcn_mfma_f32_16x16x32_bf16(a_h[r], b_l[c], acc[r][c], 0, 0, 0);
          acc[r][c] = __builtin_amdgcn_mfma_f32_16x16x32_bf16(a_l[r], b_h[c], acc[r][c], 0, 0, 0);
        }
    }
    __syncthreads();
  }
  // epilogue: scale by dinv, pack bf16, transpose via LDS, dwordx4 stores
#pragma unroll
  for (int r = 0; r < 2; ++r)
#pragma unroll
    for (int q = 0; q < 4; ++q) {
      int nl = w * 32 + r * 16 + l4 * 4 + q;
      int node = node0 + nl;
      if (node < N_NODES) {
        float dv = dinv[node];
#pragma unroll
        for (int c = 0; c < 4; ++c)
          Ah[nl * APAD + c * 16 + l15] = f2bf(acc[r][c][q] * dv);
      }
    }
  __syncthreads();
#pragma unroll
  for (int p = 0; p < 4; ++p) {
    int row = p * 32 + (t >> 3);
    int seg = t & 7;
    int node = node0 + row;
    if (node < N_NODES) {
      uint4 v = *reinterpret_cast<const uint4*>(&Ah[row * APAD + seg * 8]);
      *reinterpret_cast<uint4*>(&hs1[(size_t)node * HIDDEN + seg * 8]) = v;
    }
  }
}

// ---- Fused layer-1 aggregation + ReLU + dropout + GEMM2 --------------------
// One wave per dst node. Gathers bf16 hs1 rows (L2/L3-resident), produces the
// post-activation h1 row one-value-per-lane, then folds gemm2's shfl-FMA loop
// in-register: gs = bf16(((relu+drop)(Â x W1 + b1)) @ W2 * dinv). Deletes the
// 51 MB h1 round-trip and one kernel launch.
__global__ __launch_bounds__(256) void agg1_kernel(const uint16_t* __restrict__ hs,
                                                   const int* __restrict__ rowstart,
                                                   const int* __restrict__ srcs,
                                                   const float* __restrict__ dinv,
                                                   const float* __restrict__ bias,
                                                   const float* __restrict__ W2,
                                                   uint16_t* __restrict__ gs) {
  __shared__ float w2s[HIDDEN * N_CLASSES + 64];   // +64 pad: lanes 40..63 read OOB-safe
  int t = threadIdx.x;
  for (int i = t; i < HIDDEN * N_CLASSES; i += 256) w2s[i] = W2[i];
  __syncthreads();
  int wid = (blockIdx.x * 256 + t) >> 6;           // one wave per dst node
  int lane = t & 63;
  if (wid >= N_NODES) return;                      // wave-uniform; no sync below
  int beg = rowstart[wid], end = rowstart[wid + 1];
  float acc = bf2f(hs[(size_t)wid * HIDDEN + lane]);  // self-loop term
  int e = beg;
  for (; e + 8 <= end; e += 8) {                   // 8 gathers in flight
    int s0 = srcs[e], s1 = srcs[e + 1], s2 = srcs[e + 2], s3 = srcs[e + 3];
    int s4 = srcs[e + 4], s5 = srcs[e + 5], s6 = srcs[e + 6], s7 = srcs[e + 7];
    float a0 = bf2f(hs[(size_t)s0 * HIDDEN + lane]);
    float a1 = bf2f(hs[(size_t)s1 * HIDDEN + lane]);
    float a2 = bf2f(hs[(size_t)s2 * HIDDEN + lane]);
    float a3 = bf2f(hs[(size_t)s3 * HIDDEN + lane]);
    float a4 = bf2f(hs[(size_t)s4 * HIDDEN + lane]);
    float a5 = bf2f(hs[(size_t)s5 * HIDDEN + lane]);
    float a6 = bf2f(hs[(size_t)s6 * HIDDEN + lane]);
    float a7 = bf2f(hs[(size_t)s7 * HIDDEN + lane]);
    acc += ((a0 + a1) + (a2 + a3)) + ((a4 + a5) + (a6 + a7));
  }
  for (; e + 4 <= end; e += 4) {
    int s0 = srcs[e], s1 = srcs[e + 1], s2 = srcs[e + 2], s3 = srcs[e + 3];
    float a0 = bf2f(hs[(size_t)s0 * HIDDEN + lane]);
    float a1 = bf2f(hs[(size_t)s1 * HIDDEN + lane]);
    float a2 = bf2f(hs[(size_t)s2 * HIDDEN + lane]);
    float a3 = bf2f(hs[(size_t)s3 * HIDDEN + lane]);
    acc += (a0 + a1) + (a2 + a3);
  }
  for (; e < end; ++e) {
    int s = srcs[e];
    acc += bf2f(hs[(size_t)s * HIDDEN + lane]);
  }
  float v = acc * dinv[wid] + bias[lane];
  v = fmaxf(v, 0.f);
  // JAX dropout, jax_threefry_partitionable=True:
  // bits(i) = o0^o1 of threefry2x32(key=(0,42), (0,i)); drop iff bit31 set.
  uint32_t i = (uint32_t)wid * 64u + (uint32_t)lane;
  uint32_t o0, o1;
  threefry2x32(0u, 42u, 0u, i, o0, o1);
  v = ((o0 ^ o1) & 0x80000000u) ? 0.f : v * 2.f;
  // fused gemm2: gs[wid][lane] = (h1_row @ W2)[lane] * dinv[wid]
  float o = 0.f;
#pragma unroll 8
  for (int j = 0; j < HIDDEN; j++) {
    float hj = __shfl(v, j);
    o += hj * w2s[j * N_CLASSES + lane];
  }
  if (lane < N_CLASSES) gs[(size_t)wid * N_CLASSES + lane] = f2bf(o * dinv[wid]);
}

// -------- Layer-2 pull aggregation: out[d]=dinv[d]*(gs[d]+sum gs[src])+b2 ---
__global__ __launch_bounds__(256) void agg2_kernel(const uint16_t* __restrict__ hs,
                                                   const int* __restrict__ rowstart,
                                                   const int* __restrict__ srcs,
                                                   const float* __restrict__ dinv,
                                                   const float* __restrict__ bias,
                                                   float* __restrict__ outp) {
  const int F = N_CLASSES;
  int wid = (blockIdx.x * 256 + threadIdx.x) >> 6;  // one wave per dst node
  int lane = threadIdx.x & 63;
  if (wid >= N_NODES) return;
  int beg = rowstart[wid], end = rowstart[wid + 1];
  float acc = 0.f;
  if (lane < F) acc = bf2f(hs[(size_t)wid * F + lane]);  // self-loop term
  int e = beg;
  for (; e + 8 <= end; e += 8) {                    // 8 gathers in flight
    int s0 = srcs[e], s1 = srcs[e + 1], s2 = srcs[e + 2], s3 = srcs[e + 3];
    int s4 = srcs[e + 4], s5 = srcs[e + 5], s6 = srcs[e + 6], s7 = srcs[e + 7];
    if (lane < F) {
      float a0 = bf2f(hs[(size_t)s0 * F + lane]);
      float a1 = bf2f(hs[(size_t)s1 * F + lane]);
      float a2 = bf2f(hs[(size_t)s2 * F + lane]);
      float a3 = bf2f(hs[(size_t)s3 * F + lane]);
      float a4 = bf2f(hs[(size_t)s4 * F + lane]);
      float a5 = bf2f(hs[(size_t)s5 * F + lane]);
      float a6 = bf2f(hs[(size_t)s6 * F + lane]);
      float a7 = bf2f(hs[(size_t)s7 * F + lane]);
      acc += ((a0 + a1) + (a2 + a3)) + ((a4 + a5) + (a6 + a7));
    }
  }
  for (; e + 4 <= end; e += 4) {
    int s0 = srcs[e], s1 = srcs[e + 1], s2 = srcs[e + 2], s3 = srcs[e + 3];
    if (lane < F) {
      float a0 = bf2f(hs[(size_t)s0 * F + lane]);
      float a1 = bf2f(hs[(size_t)s1 * F + lane]);
      float a2 = bf2f(hs[(size_t)s2 * F + lane]);
      float a3 = bf2f(hs[(size_t)s3 * F + lane]);
      acc += (a0 + a1) + (a2 + a3);
    }
  }
  for (; e < end; ++e) {
    int s = srcs[e];
    if (lane < F) acc += bf2f(hs[(size_t)s * F + lane]);
  }
  if (lane < F)
    outp[(size_t)wid * F + lane] = acc * dinv[wid] + bias[lane];
}

// ---------------- launch -----------------------------------------------------
extern "C" void kernel_launch(void* const* d_in, const int* in_sizes, int n_in,
                              void* d_out, int out_size, void* d_ws, size_t ws_size,
                              hipStream_t stream) {
  const float* x   = (const float*)d_in[0];
  const int* edges = (const int*)d_in[1];  // [2*E] int32: row0=src, row1=dst
  const float* W1  = (const float*)d_in[2];
  const float* b1  = (const float*)d_in[3];
  const float* W2  = (const float*)d_in[4];
  const float* b2  = (const float*)d_in[5];
  float* out = (float*)d_out;

  char* ws = (char*)d_ws;
  size_t off = 0;
  auto alloc = [&](size_t bytes) -> void* {
    void* p = ws + off;
    off = (off + bytes + 255) & ~(size_t)255;
    return p;
  };
  int*      rowstart = (int*)alloc((size_t)(N_NODES + 1) * 4);
  float*    dinv     = (float*)alloc((size_t)N_NODES * 4);
  int*      deg      = (int*)alloc((size_t)N_NODES * 4);
  int*      cur      = (int*)alloc((size_t)N_NODES * 4);
  int*      bsum     = (int*)alloc(256 * 4);
  int*      srcs     = (int*)alloc((size_t)N_EDGES * 4);
  uint16_t* hs1      = (uint16_t*)alloc((size_t)N_NODES * HIDDEN * 2);
  uint16_t* gs       = (uint16_t*)alloc((size_t)N_NODES * N_CLASSES * 2);
  uint16_t* Wth      = (uint16_t*)alloc((size_t)HIDDEN * N_FEAT * 2);
  uint16_t* Wtl      = (uint16_t*)alloc((size_t)HIDDEN * N_FEAT * 2);

  zero_kernel<<<(N_NODES + 255) / 256, 256, 0, stream>>>(deg);
  wprep_kernel<<<(HIDDEN * N_FEAT) / 256, 256, 0, stream>>>(W1, Wth, Wtl);
  deg_kernel<<<N_EDGES / 4 / 256, 256, 0, stream>>>(edges, deg);
  scan1_kernel<<<NBLK, SCB, 0, stream>>>(deg, rowstart, bsum, dinv);
  scan2_kernel<<<1, 128, 0, stream>>>(bsum);
  scan3_kernel<<<NBLK, SCB, 0, stream>>>(rowstart, bsum, cur);
  scatter_kernel<<<N_EDGES / 4 / 256, 256, 0, stream>>>(edges, cur, srcs);
  gemm1_kernel<<<(N_NODES + 127) / 128, 256, 0, stream>>>(x, Wth, Wtl, dinv, hs1);
  agg1_kernel<<<(N_NODES * 64 + 255) / 256, 256, 0, stream>>>(
      hs1, rowstart, srcs, dinv, b1, W2, gs);
  agg2_kernel<<<(N_NODES * 64 + 255) / 256, 256, 0, stream>>>(
      gs, rowstart, srcs, dinv, b2, out);
}

// Round 3
// 604.638 us; speedup vs baseline: 1.5220x; 1.5220x over previous
//
#include <hip/hip_runtime.h>
#include <stdint.h>

#define N_NODES   100000
#define N_EDGES   3200000
#define N_FEAT    512
#define HIDDEN    64
#define N_CLASSES 40

#define BSH   9                      // bucket = dst >> 9 (512 nodes per bucket)
#define NB    196                    // ceil(100000/512)
#define CAP   18432                  // bucket region capacity; mean 16384, +16 sigma
#define CHUNK 4096                   // edges per bin_kernel workgroup

// ---------------- bf16 helpers (RNE) ----------------------------------------
__device__ __forceinline__ float bf2f(uint16_t u) {
  return __uint_as_float((uint32_t)u << 16);
}
__device__ __forceinline__ uint16_t f2bf(float f) {
  uint32_t x = __float_as_uint(f);
  return (uint16_t)((x + 0x7fffu + ((x >> 16) & 1u)) >> 16);
}

// ---------------- threefry2x32 (exact JAX semantics, key = (0,42)) ----------
__device__ __forceinline__ uint32_t rotl32(uint32_t x, uint32_t r) {
  return (x << r) | (x >> (32u - r));
}

__device__ __forceinline__ void threefry2x32(uint32_t k0, uint32_t k1,
                                             uint32_t x0, uint32_t x1,
                                             uint32_t& o0, uint32_t& o1) {
  uint32_t ks2 = k0 ^ k1 ^ 0x1BD11BDAu;
  x0 += k0; x1 += k1;
#define TF_R4(a,b,c,d) \
  x0 += x1; x1 = rotl32(x1,a); x1 ^= x0; \
  x0 += x1; x1 = rotl32(x1,b); x1 ^= x0; \
  x0 += x1; x1 = rotl32(x1,c); x1 ^= x0; \
  x0 += x1; x1 = rotl32(x1,d); x1 ^= x0;
  TF_R4(13,15,26,6)   x0 += k1;  x1 += ks2 + 1u;
  TF_R4(17,29,16,24)  x0 += ks2; x1 += k0  + 2u;
  TF_R4(13,15,26,6)   x0 += k0;  x1 += k1  + 3u;
  TF_R4(17,29,16,24)  x0 += k1;  x1 += ks2 + 4u;
  TF_R4(13,15,26,6)   x0 += ks2; x1 += k0  + 5u;
#undef TF_R4
  o0 = x0; o1 = x1;
}

// ---------------- CSR build (bucket-binned; no per-edge global atomics) ------
// NOTE (round-2 lesson): the "1 atomic per edge" scatter variant measured
// 280 us — cross-XCD atomic round-trips + 15x HBM write amplification on
// random 4B stores (WRITE_SIZE 195 MB for a 12.8 MB buffer). LDS-staged
// bucket binning with sequential region writes is the right structure here.
__global__ void init_kernel(int* __restrict__ gcursor) {
  int t = threadIdx.x;
  if (t < NB) gcursor[t] = t * CAP;  // fixed-capacity bucket regions
}

__global__ __launch_bounds__(256) void bin_kernel(const int* __restrict__ edges,
                                                  int* __restrict__ gcursor,
                                                  uint32_t* __restrict__ gbins) {
  __shared__ int bcnt[256];
  __shared__ int sc[256];
  __shared__ int bs[NB + 1];
  __shared__ int gbase[NB];
  __shared__ uint32_t sorted[CHUNK];

  int t = threadIdx.x;
  int base = blockIdx.x * CHUNK;
  int s[16], d[16], pos[16];
#pragma unroll
  for (int i = 0; i < 16; i++) {
    int e = base + i * 256 + t;
    if (e < N_EDGES) { s[i] = edges[e]; d[i] = edges[N_EDGES + e]; }
    else d[i] = -1;
  }
  bcnt[t] = 0;
  __syncthreads();
#pragma unroll
  for (int i = 0; i < 16; i++)
    if (d[i] >= 0) pos[i] = atomicAdd(&bcnt[d[i] >> BSH], 1);
  __syncthreads();
  sc[t] = bcnt[t];
  __syncthreads();
  for (int off = 1; off < 256; off <<= 1) {       // Hillis-Steele inclusive scan
    int v = (t >= off) ? sc[t - off] : 0;
    __syncthreads();
    sc[t] += v;
    __syncthreads();
  }
  if (t < NB) bs[t] = sc[t] - bcnt[t];            // exclusive starts
  if (t == 255) bs[NB] = sc[255];
  if (t < NB && bcnt[t] > 0) gbase[t] = atomicAdd(&gcursor[t], bcnt[t]);
  __syncthreads();
#pragma unroll
  for (int i = 0; i < 16; i++)
    if (d[i] >= 0)
      sorted[bs[d[i] >> BSH] + pos[i]] =
          ((uint32_t)s[i] << BSH) | ((uint32_t)d[i] & ((1u << BSH) - 1));
  __syncthreads();
  int total = bs[NB];
  for (int p = t; p < total; p += 256) {
    int lo = 0, hi = NB - 1;                      // bucket: bs[b] <= p < bs[b+1]
    while (lo < hi) { int mid = (lo + hi + 1) >> 1; if (bs[mid] <= p) lo = mid; else hi = mid - 1; }
    gbins[gbase[lo] + (p - bs[lo])] = sorted[p];
  }
}

__global__ void sizes_scan(const int* __restrict__ gcursor, int* __restrict__ bstart,
                           int* __restrict__ rowstart) {
  __shared__ int s[256];
  int t = threadIdx.x;
  int v = (t < NB) ? (gcursor[t] - t * CAP) : 0;
  s[t] = v; __syncthreads();
  for (int off = 1; off < 256; off <<= 1) {
    int a = (t >= off) ? s[t - off] : 0;
    __syncthreads();
    s[t] += a;
    __syncthreads();
  }
  if (t < NB) bstart[t] = s[t] - v;
  if (t == 255) bstart[NB] = s[255];              // == N_EDGES
  if (t == 0) rowstart[N_NODES] = N_EDGES;
}

__global__ __launch_bounds__(512) void node_kernel(const uint32_t* __restrict__ gbins,
                                                   const int* __restrict__ bstart,
                                                   int* __restrict__ rowstart,
                                                   int* __restrict__ srcs,
                                                   float* __restrict__ dinv) {
  __shared__ int deg[512];
  __shared__ int loc[512];
  __shared__ int cur[512];
  int b = blockIdx.x, t = threadIdx.x;
  int rbase = b * CAP;
  int obase = bstart[b];
  int sz = bstart[b + 1] - obase;
  deg[t] = 0;
  __syncthreads();
  for (int p = t; p < sz; p += 512)
    atomicAdd(&deg[gbins[rbase + p] & ((1u << BSH) - 1)], 1);
  __syncthreads();
  int v = deg[t];
  loc[t] = v;
  __syncthreads();
  for (int off = 1; off < 512; off <<= 1) {       // inclusive scan
    int a = (t >= off) ? loc[t - off] : 0;
    __syncthreads();
    loc[t] += a;
    __syncthreads();
  }
  int excl = loc[t] - v;
  cur[t] = excl;
  int node = (b << BSH) + t;
  if (node < N_NODES) {
    rowstart[node] = obase + excl;
    dinv[node] = rsqrtf((float)(v + 1));          // +1 self-loop
  }
  __syncthreads();
  for (int p = t; p < sz; p += 512) {
    uint32_t e = gbins[rbase + p];
    int pos = atomicAdd(&cur[e & ((1u << BSH) - 1)], 1);
    srcs[obase + pos] = (int)(e >> BSH);
  }
}

// ---------------- W1 prep: split-transpose to bf16 hi/lo --------------------
__global__ __launch_bounds__(256) void wprep_kernel(const float* __restrict__ W1,
                                                    uint16_t* __restrict__ Wth,
                                                    uint16_t* __restrict__ Wtl) {
  int id = blockIdx.x * 256 + threadIdx.x;        // 64*512 = 32768 total
  int col = id >> 9, k = id & 511;
  float v = W1[(size_t)k * HIDDEN + col];
  uint32_t u = __float_as_uint(v);
  uint32_t hb = u & 0xffff0000u;                  // truncated bf16 hi
  float lo = v - __uint_as_float(hb);             // exact residual
  Wth[id] = (uint16_t)(u >> 16);
  Wtl[id] = (uint16_t)(__float_as_uint(lo) >> 16);
}

// ---------------- GEMM1: hs1 = bf16((x @ W1) * dinv[n]) via bf16x3 MFMA -----
typedef __bf16 bf16x8 __attribute__((ext_vector_type(8)));
typedef float  f32x4  __attribute__((ext_vector_type(4)));

#define APAD 72   // LDS row stride in bf16 elems (144 B -> 2-way = free on b128)

__global__ __launch_bounds__(256, 2) void gemm1_kernel(
    const float* __restrict__ x, const uint16_t* __restrict__ Wth,
    const uint16_t* __restrict__ Wtl, const float* __restrict__ dinv,
    uint16_t* __restrict__ hs1) {
  __shared__ __align__(16) uint16_t Ah[128 * APAD];
  __shared__ __align__(16) uint16_t Al[128 * APAD];
  __shared__ __align__(16) uint16_t Bh[64 * APAD];
  __shared__ __align__(16) uint16_t Bl[64 * APAD];

  int t = threadIdx.x;
  int node0 = blockIdx.x * 128;
  int w = t >> 6, l = t & 63;
  int l15 = l & 15, l4 = l >> 4;

  f32x4 acc[2][4];
#pragma unroll
  for (int r = 0; r < 2; r++)
#pragma unroll
    for (int c = 0; c < 4; c++) acc[r][c] = (f32x4){0.f, 0.f, 0.f, 0.f};

  int an = t >> 4;            // node-sub per A pass (0..15)
  int ak = (t & 15) * 4;      // k0 within chunk for A staging
  int bc = t >> 3;            // col-sub per B pass (0..31)
  int bk = (t & 7) * 8;       // k0 within chunk for B staging

  for (int kc = 0; kc < N_FEAT; kc += 64) {
#pragma unroll
    for (int p = 0; p < 2; ++p) {
      int col = p * 32 + bc;
      *reinterpret_cast<uint4*>(&Bh[col * APAD + bk]) =
          *reinterpret_cast<const uint4*>(&Wth[(size_t)col * N_FEAT + kc + bk]);
      *reinterpret_cast<uint4*>(&Bl[col * APAD + bk]) =
          *reinterpret_cast<const uint4*>(&Wtl[(size_t)col * N_FEAT + kc + bk]);
    }
#pragma unroll
    for (int p = 0; p < 8; ++p) {
      int nl = p * 16 + an;
      int gr = node0 + nl; if (gr > N_NODES - 1) gr = N_NODES - 1;
      const float4 v = *reinterpret_cast<const float4*>(&x[(size_t)gr * N_FEAT + kc + ak]);
      uint32_t u0 = __float_as_uint(v.x), u1 = __float_as_uint(v.y);
      uint32_t u2 = __float_as_uint(v.z), u3 = __float_as_uint(v.w);
      float f0 = v.x - __uint_as_float(u0 & 0xffff0000u);
      float f1 = v.y - __uint_as_float(u1 & 0xffff0000u);
      float f2 = v.z - __uint_as_float(u2 & 0xffff0000u);
      float f3 = v.w - __uint_as_float(u3 & 0xffff0000u);
      uint32_t hi01 = (u0 >> 16) | (u1 & 0xffff0000u);
      uint32_t hi23 = (u2 >> 16) | (u3 & 0xffff0000u);
      uint32_t lo01 = (__float_as_uint(f0) >> 16) | (__float_as_uint(f1) & 0xffff0000u);
      uint32_t lo23 = (__float_as_uint(f2) >> 16) | (__float_as_uint(f3) & 0xffff0000u);
      *reinterpret_cast<uint2*>(&Ah[nl * APAD + ak]) = make_uint2(hi01, hi23);
      *reinterpret_cast<uint2*>(&Al[nl * APAD + ak]) = make_uint2(lo01, lo23);
    }
    __syncthreads();
#pragma unroll
    for (int s = 0; s < 2; ++s) {
      int ko = s * 32 + l4 * 8;
      bf16x8 a_h[2], a_l[2], b_h[4], b_l[4];
#pragma unroll
      for (int r = 0; r < 2; ++r) {
        int row = w * 32 + r * 16 + l15;
        a_h[r] = *reinterpret_cast<const bf16x8*>(&Ah[row * APAD + ko]);
        a_l[r] = *reinterpret_cast<const bf16x8*>(&Al[row * APAD + ko]);
      }
#pragma unroll
      for (int c = 0; c < 4; ++c) {
        int col = c * 16 + l15;
        b_h[c] = *reinterpret_cast<const bf16x8*>(&Bh[col * APAD + ko]);
        b_l[c] = *reinterpret_cast<const bf16x8*>(&Bl[col * APAD + ko]);
      }
#pragma unroll
      for (int r = 0; r < 2; ++r)
#pragma unroll
        for (int c = 0; c < 4; ++c) {
          acc[r][c] = __builtin_amdgcn_mfma_f32_16x16x32_bf16(a_h[r], b_h[c], acc[r][c], 0, 0, 0);
          acc[r][c] = __builtin_amdgcn_mfma_f32_16x16x32_bf16(a_h[r], b_l[c], acc[r][c], 0, 0, 0);
          acc[r][c] = __builtin_amdgcn_mfma_f32_16x16x32_bf16(a_l[r], b_h[c], acc[r][c], 0, 0, 0);
        }
    }
    __syncthreads();
  }
  // epilogue: scale by dinv, pack bf16, transpose via LDS, dwordx4 stores
#pragma unroll
  for (int r = 0; r < 2; ++r)
#pragma unroll
    for (int q = 0; q < 4; ++q) {
      int nl = w * 32 + r * 16 + l4 * 4 + q;
      int node = node0 + nl;
      if (node < N_NODES) {
        float dv = dinv[node];
#pragma unroll
        for (int c = 0; c < 4; ++c)
          Ah[nl * APAD + c * 16 + l15] = f2bf(acc[r][c][q] * dv);
      }
    }
  __syncthreads();
#pragma unroll
  for (int p = 0; p < 4; ++p) {
    int row = p * 32 + (t >> 3);
    int seg = t & 7;
    int node = node0 + row;
    if (node < N_NODES) {
      uint4 v = *reinterpret_cast<const uint4*>(&Ah[row * APAD + seg * 8]);
      *reinterpret_cast<uint4*>(&hs1[(size_t)node * HIDDEN + seg * 8]) = v;
    }
  }
}

// ---- Fused layer-1 aggregation + ReLU + dropout + GEMM2 --------------------
// One wave per dst node. Gathers bf16 hs1 rows, produces the post-activation
// h1 row one-value-per-lane, then folds gemm2's shfl-FMA loop in-register:
// gs = bf16(((relu+drop)(Â x W1 + b1)) @ W2 * dinv). Deletes the 51 MB h1
// round-trip and one kernel launch.
__global__ __launch_bounds__(256) void agg1_kernel(const uint16_t* __restrict__ hs,
                                                   const int* __restrict__ rowstart,
                                                   const int* __restrict__ srcs,
                                                   const float* __restrict__ dinv,
                                                   const float* __restrict__ bias,
                                                   const float* __restrict__ W2,
                                                   uint16_t* __restrict__ gs) {
  __shared__ float w2s[HIDDEN * N_CLASSES + 64];  // +64 pad: lanes 40..63 OOB-safe
  int t = threadIdx.x;
  for (int i = t; i < HIDDEN * N_CLASSES; i += 256) w2s[i] = W2[i];
  __syncthreads();
  int wid = (blockIdx.x * 256 + t) >> 6;          // one wave per dst node
  int lane = t & 63;
  if (wid >= N_NODES) return;                     // wave-uniform; no sync below
  int beg = rowstart[wid], end = rowstart[wid + 1];
  float acc = bf2f(hs[(size_t)wid * HIDDEN + lane]);  // self-loop term
  int e = beg;
  for (; e + 8 <= end; e += 8) {                  // 8 gathers in flight
    int s0 = srcs[e], s1 = srcs[e + 1], s2 = srcs[e + 2], s3 = srcs[e + 3];
    int s4 = srcs[e + 4], s5 = srcs[e + 5], s6 = srcs[e + 6], s7 = srcs[e + 7];
    float a0 = bf2f(hs[(size_t)s0 * HIDDEN + lane]);
    float a1 = bf2f(hs[(size_t)s1 * HIDDEN + lane]);
    float a2 = bf2f(hs[(size_t)s2 * HIDDEN + lane]);
    float a3 = bf2f(hs[(size_t)s3 * HIDDEN + lane]);
    float a4 = bf2f(hs[(size_t)s4 * HIDDEN + lane]);
    float a5 = bf2f(hs[(size_t)s5 * HIDDEN + lane]);
    float a6 = bf2f(hs[(size_t)s6 * HIDDEN + lane]);
    float a7 = bf2f(hs[(size_t)s7 * HIDDEN + lane]);
    acc += ((a0 + a1) + (a2 + a3)) + ((a4 + a5) + (a6 + a7));
  }
  for (; e + 4 <= end; e += 4) {
    int s0 = srcs[e], s1 = srcs[e + 1], s2 = srcs[e + 2], s3 = srcs[e + 3];
    float a0 = bf2f(hs[(size_t)s0 * HIDDEN + lane]);
    float a1 = bf2f(hs[(size_t)s1 * HIDDEN + lane]);
    float a2 = bf2f(hs[(size_t)s2 * HIDDEN + lane]);
    float a3 = bf2f(hs[(size_t)s3 * HIDDEN + lane]);
    acc += (a0 + a1) + (a2 + a3);
  }
  for (; e < end; ++e) {
    int s = srcs[e];
    acc += bf2f(hs[(size_t)s * HIDDEN + lane]);
  }
  float v = acc * dinv[wid] + bias[lane];
  v = fmaxf(v, 0.f);
  // JAX dropout, jax_threefry_partitionable=True:
  // bits(i) = o0^o1 of threefry2x32(key=(0,42), (0,i)); drop iff bit31 set.
  uint32_t i = (uint32_t)wid * 64u + (uint32_t)lane;
  uint32_t o0, o1;
  threefry2x32(0u, 42u, 0u, i, o0, o1);
  v = ((o0 ^ o1) & 0x80000000u) ? 0.f : v * 2.f;
  // fused gemm2: gs[wid][lane] = (h1_row @ W2)[lane] * dinv[wid]
  float o = 0.f;
#pragma unroll 8
  for (int j = 0; j < HIDDEN; j++) {
    float hj = __shfl(v, j);
    o += hj * w2s[j * N_CLASSES + lane];
  }
  if (lane < N_CLASSES) gs[(size_t)wid * N_CLASSES + lane] = f2bf(o * dinv[wid]);
}

// -------- Layer-2 pull aggregation: out[d]=dinv[d]*(gs[d]+sum gs[src])+b2 ---
__global__ __launch_bounds__(256) void agg2_kernel(const uint16_t* __restrict__ hs,
                                                   const int* __restrict__ rowstart,
                                                   const int* __restrict__ srcs,
                                                   const float* __restrict__ dinv,
                                                   const float* __restrict__ bias,
                                                   float* __restrict__ outp) {
  const int F = N_CLASSES;
  int wid = (blockIdx.x * 256 + threadIdx.x) >> 6;  // one wave per dst node
  int lane = threadIdx.x & 63;
  if (wid >= N_NODES) return;
  int beg = rowstart[wid], end = rowstart[wid + 1];
  float acc = 0.f;
  if (lane < F) acc = bf2f(hs[(size_t)wid * F + lane]);  // self-loop term
  int e = beg;
  for (; e + 8 <= end; e += 8) {                    // 8 gathers in flight
    int s0 = srcs[e], s1 = srcs[e + 1], s2 = srcs[e + 2], s3 = srcs[e + 3];
    int s4 = srcs[e + 4], s5 = srcs[e + 5], s6 = srcs[e + 6], s7 = srcs[e + 7];
    if (lane < F) {
      float a0 = bf2f(hs[(size_t)s0 * F + lane]);
      float a1 = bf2f(hs[(size_t)s1 * F + lane]);
      float a2 = bf2f(hs[(size_t)s2 * F + lane]);
      float a3 = bf2f(hs[(size_t)s3 * F + lane]);
      float a4 = bf2f(hs[(size_t)s4 * F + lane]);
      float a5 = bf2f(hs[(size_t)s5 * F + lane]);
      float a6 = bf2f(hs[(size_t)s6 * F + lane]);
      float a7 = bf2f(hs[(size_t)s7 * F + lane]);
      acc += ((a0 + a1) + (a2 + a3)) + ((a4 + a5) + (a6 + a7));
    }
  }
  for (; e + 4 <= end; e += 4) {
    int s0 = srcs[e], s1 = srcs[e + 1], s2 = srcs[e + 2], s3 = srcs[e + 3];
    if (lane < F) {
      float a0 = bf2f(hs[(size_t)s0 * F + lane]);
      float a1 = bf2f(hs[(size_t)s1 * F + lane]);
      float a2 = bf2f(hs[(size_t)s2 * F + lane]);
      float a3 = bf2f(hs[(size_t)s3 * F + lane]);
      acc += (a0 + a1) + (a2 + a3);
    }
  }
  for (; e < end; ++e) {
    int s = srcs[e];
    if (lane < F) acc += bf2f(hs[(size_t)s * F + lane]);
  }
  if (lane < F)
    outp[(size_t)wid * F + lane] = acc * dinv[wid] + bias[lane];
}

// ---------------- launch -----------------------------------------------------
extern "C" void kernel_launch(void* const* d_in, const int* in_sizes, int n_in,
                              void* d_out, int out_size, void* d_ws, size_t ws_size,
                              hipStream_t stream) {
  const float* x   = (const float*)d_in[0];
  const int* edges = (const int*)d_in[1];  // [2*E] int32: row0=src, row1=dst
  const float* W1  = (const float*)d_in[2];
  const float* b1  = (const float*)d_in[3];
  const float* W2  = (const float*)d_in[4];
  const float* b2  = (const float*)d_in[5];
  float* out = (float*)d_out;

  char* ws = (char*)d_ws;
  size_t off = 0;
  auto alloc = [&](size_t bytes) -> void* {
    void* p = ws + off;
    off = (off + bytes + 255) & ~(size_t)255;
    return p;
  };
  int*      rowstart = (int*)alloc((size_t)(N_NODES + 1) * 4);
  float*    dinv     = (float*)alloc((size_t)N_NODES * 4);
  int*      gcursor  = (int*)alloc(256 * 4);
  int*      bstart   = (int*)alloc(256 * 4);
  int*      srcs     = (int*)alloc((size_t)N_EDGES * 4);
  uint32_t* gbins    = (uint32_t*)alloc((size_t)NB * CAP * 4);
  uint16_t* hs1      = (uint16_t*)alloc((size_t)N_NODES * HIDDEN * 2);
  uint16_t* gs       = (uint16_t*)alloc((size_t)N_NODES * N_CLASSES * 2);
  uint16_t* Wth      = (uint16_t*)alloc((size_t)HIDDEN * N_FEAT * 2);
  uint16_t* Wtl      = (uint16_t*)alloc((size_t)HIDDEN * N_FEAT * 2);

  init_kernel<<<1, 256, 0, stream>>>(gcursor);
  wprep_kernel<<<(HIDDEN * N_FEAT) / 256, 256, 0, stream>>>(W1, Wth, Wtl);
  bin_kernel<<<(N_EDGES + CHUNK - 1) / CHUNK, 256, 0, stream>>>(edges, gcursor, gbins);
  sizes_scan<<<1, 256, 0, stream>>>(gcursor, bstart, rowstart);
  node_kernel<<<NB, 512, 0, stream>>>(gbins, bstart, rowstart, srcs, dinv);
  gemm1_kernel<<<(N_NODES + 127) / 128, 256, 0, stream>>>(x, Wth, Wtl, dinv, hs1);
  agg1_kernel<<<(N_NODES * 64 + 255) / 256, 256, 0, stream>>>(
      hs1, rowstart, srcs, dinv, b1, W2, gs);
  agg2_kernel<<<(N_NODES * 64 + 255) / 256, 256, 0, stream>>>(
      gs, rowstart, srcs, dinv, b2, out);
}

// Round 4
// 602.501 us; speedup vs baseline: 1.5274x; 1.0035x over previous
//
#include <hip/hip_runtime.h>
#include <stdint.h>

#define N_NODES   100000
#define N_EDGES   3200000
#define N_FEAT    512
#define HIDDEN    64
#define N_CLASSES 40

#define BSH   9                      // bucket = dst >> 9 (512 nodes per bucket)
#define NB    196                    // ceil(100000/512)
#define CAP   18432                  // bucket region capacity; mean 16384, +16 sigma
#define CHUNK 4096                   // edges per bin_kernel workgroup

// ---------------- bf16 helpers (RNE) ----------------------------------------
__device__ __forceinline__ float bf2f(uint16_t u) {
  return __uint_as_float((uint32_t)u << 16);
}
__device__ __forceinline__ uint16_t f2bf(float f) {
  uint32_t x = __float_as_uint(f);
  return (uint16_t)((x + 0x7fffu + ((x >> 16) & 1u)) >> 16);
}
// unpack a dword holding two bf16 (low = even feat, high = odd feat)
__device__ __forceinline__ float bflo(uint32_t a) { return __uint_as_float(a << 16); }
__device__ __forceinline__ float bfhi(uint32_t a) { return __uint_as_float(a & 0xffff0000u); }

// ---------------- threefry2x32 (exact JAX semantics, key = (0,42)) ----------
__device__ __forceinline__ uint32_t rotl32(uint32_t x, uint32_t r) {
  return (x << r) | (x >> (32u - r));
}

__device__ __forceinline__ void threefry2x32(uint32_t k0, uint32_t k1,
                                             uint32_t x0, uint32_t x1,
                                             uint32_t& o0, uint32_t& o1) {
  uint32_t ks2 = k0 ^ k1 ^ 0x1BD11BDAu;
  x0 += k0; x1 += k1;
#define TF_R4(a,b,c,d) \
  x0 += x1; x1 = rotl32(x1,a); x1 ^= x0; \
  x0 += x1; x1 = rotl32(x1,b); x1 ^= x0; \
  x0 += x1; x1 = rotl32(x1,c); x1 ^= x0; \
  x0 += x1; x1 = rotl32(x1,d); x1 ^= x0;
  TF_R4(13,15,26,6)   x0 += k1;  x1 += ks2 + 1u;
  TF_R4(17,29,16,24)  x0 += ks2; x1 += k0  + 2u;
  TF_R4(13,15,26,6)   x0 += k0;  x1 += k1  + 3u;
  TF_R4(17,29,16,24)  x0 += k1;  x1 += ks2 + 4u;
  TF_R4(13,15,26,6)   x0 += ks2; x1 += k0  + 5u;
#undef TF_R4
  o0 = x0; o1 = x1;
}

// ---------------- CSR build (bucket-binned; no per-edge global atomics) ------
// (round-2 lesson: 1-atomic-per-edge scatter = 280 us — cross-XCD atomic
//  round-trips + 15x HBM write amplification on random 4B stores.)
__global__ void init_kernel(int* __restrict__ gcursor) {
  int t = threadIdx.x;
  if (t < NB) gcursor[t] = t * CAP;  // fixed-capacity bucket regions
}

__global__ __launch_bounds__(256) void bin_kernel(const int* __restrict__ edges,
                                                  int* __restrict__ gcursor,
                                                  uint32_t* __restrict__ gbins) {
  __shared__ int bcnt[256];
  __shared__ int sc[256];
  __shared__ int bs[NB + 1];
  __shared__ int gbase[NB];
  __shared__ uint32_t sorted[CHUNK];

  int t = threadIdx.x;
  int base = blockIdx.x * CHUNK;
  int s[16], d[16], pos[16];
#pragma unroll
  for (int i = 0; i < 16; i++) {
    int e = base + i * 256 + t;
    if (e < N_EDGES) { s[i] = edges[e]; d[i] = edges[N_EDGES + e]; }
    else d[i] = -1;
  }
  bcnt[t] = 0;
  __syncthreads();
#pragma unroll
  for (int i = 0; i < 16; i++)
    if (d[i] >= 0) pos[i] = atomicAdd(&bcnt[d[i] >> BSH], 1);
  __syncthreads();
  sc[t] = bcnt[t];
  __syncthreads();
  for (int off = 1; off < 256; off <<= 1) {       // Hillis-Steele inclusive scan
    int v = (t >= off) ? sc[t - off] : 0;
    __syncthreads();
    sc[t] += v;
    __syncthreads();
  }
  if (t < NB) bs[t] = sc[t] - bcnt[t];            // exclusive starts
  if (t == 255) bs[NB] = sc[255];
  if (t < NB && bcnt[t] > 0) gbase[t] = atomicAdd(&gcursor[t], bcnt[t]);
  __syncthreads();
#pragma unroll
  for (int i = 0; i < 16; i++)
    if (d[i] >= 0)
      sorted[bs[d[i] >> BSH] + pos[i]] =
          ((uint32_t)s[i] << BSH) | ((uint32_t)d[i] & ((1u << BSH) - 1));
  __syncthreads();
  int total = bs[NB];
  for (int p = t; p < total; p += 256) {
    int lo = 0, hi = NB - 1;                      // bucket: bs[b] <= p < bs[b+1]
    while (lo < hi) { int mid = (lo + hi + 1) >> 1; if (bs[mid] <= p) lo = mid; else hi = mid - 1; }
    gbins[gbase[lo] + (p - bs[lo])] = sorted[p];
  }
}

__global__ void sizes_scan(const int* __restrict__ gcursor, int* __restrict__ bstart,
                           int* __restrict__ rowstart) {
  __shared__ int s[256];
  int t = threadIdx.x;
  int v = (t < NB) ? (gcursor[t] - t * CAP) : 0;
  s[t] = v; __syncthreads();
  for (int off = 1; off < 256; off <<= 1) {
    int a = (t >= off) ? s[t - off] : 0;
    __syncthreads();
    s[t] += a;
    __syncthreads();
  }
  if (t < NB) bstart[t] = s[t] - v;
  if (t == 255) bstart[NB] = s[255];              // == N_EDGES
  if (t == 0) rowstart[N_NODES] = N_EDGES;
}

__global__ __launch_bounds__(512) void node_kernel(const uint32_t* __restrict__ gbins,
                                                   const int* __restrict__ bstart,
                                                   int* __restrict__ rowstart,
                                                   int* __restrict__ srcs,
                                                   float* __restrict__ dinv) {
  __shared__ int deg[512];
  __shared__ int loc[512];
  __shared__ int cur[512];
  int b = blockIdx.x, t = threadIdx.x;
  int rbase = b * CAP;
  int obase = bstart[b];
  int sz = bstart[b + 1] - obase;
  deg[t] = 0;
  __syncthreads();
  for (int p = t; p < sz; p += 512)
    atomicAdd(&deg[gbins[rbase + p] & ((1u << BSH) - 1)], 1);
  __syncthreads();
  int v = deg[t];
  loc[t] = v;
  __syncthreads();
  for (int off = 1; off < 512; off <<= 1) {       // inclusive scan
    int a = (t >= off) ? loc[t - off] : 0;
    __syncthreads();
    loc[t] += a;
    __syncthreads();
  }
  int excl = loc[t] - v;
  cur[t] = excl;
  int node = (b << BSH) + t;
  if (node < N_NODES) {
    rowstart[node] = obase + excl;
    dinv[node] = rsqrtf((float)(v + 1));          // +1 self-loop
  }
  __syncthreads();
  for (int p = t; p < sz; p += 512) {
    uint32_t e = gbins[rbase + p];
    int pos = atomicAdd(&cur[e & ((1u << BSH) - 1)], 1);
    srcs[obase + pos] = (int)(e >> BSH);
  }
}

// ---------------- W1 prep: split-transpose to bf16 hi/lo --------------------
__global__ __launch_bounds__(256) void wprep_kernel(const float* __restrict__ W1,
                                                    uint16_t* __restrict__ Wth,
                                                    uint16_t* __restrict__ Wtl) {
  int id = blockIdx.x * 256 + threadIdx.x;        // 64*512 = 32768 total
  int col = id >> 9, k = id & 511;
  float v = W1[(size_t)k * HIDDEN + col];
  uint32_t u = __float_as_uint(v);
  uint32_t hb = u & 0xffff0000u;                  // truncated bf16 hi
  float lo = v - __uint_as_float(hb);             // exact residual
  Wth[id] = (uint16_t)(u >> 16);
  Wtl[id] = (uint16_t)(__float_as_uint(lo) >> 16);
}

// ---------------- GEMM1: hs1 = bf16((x @ W1) * dinv[n]) via bf16x3 MFMA -----
typedef __bf16 bf16x8 __attribute__((ext_vector_type(8)));
typedef float  f32x4  __attribute__((ext_vector_type(4)));

#define APAD 72   // LDS row stride in bf16 elems (144 B -> 2-way = free on b128)

__global__ __launch_bounds__(256, 2) void gemm1_kernel(
    const float* __restrict__ x, const uint16_t* __restrict__ Wth,
    const uint16_t* __restrict__ Wtl, const float* __restrict__ dinv,
    uint16_t* __restrict__ hs1) {
  __shared__ __align__(16) uint16_t Ah[128 * APAD];
  __shared__ __align__(16) uint16_t Al[128 * APAD];
  __shared__ __align__(16) uint16_t Bh[64 * APAD];
  __shared__ __align__(16) uint16_t Bl[64 * APAD];

  int t = threadIdx.x;
  int node0 = blockIdx.x * 128;
  int w = t >> 6, l = t & 63;
  int l15 = l & 15, l4 = l >> 4;

  f32x4 acc[2][4];
#pragma unroll
  for (int r = 0; r < 2; r++)
#pragma unroll
    for (int c = 0; c < 4; c++) acc[r][c] = (f32x4){0.f, 0.f, 0.f, 0.f};

  int an = t >> 4;            // node-sub per A pass (0..15)
  int ak = (t & 15) * 4;      // k0 within chunk for A staging
  int bc = t >> 3;            // col-sub per B pass (0..31)
  int bk = (t & 7) * 8;       // k0 within chunk for B staging

  for (int kc = 0; kc < N_FEAT; kc += 64) {
#pragma unroll
    for (int p = 0; p < 2; ++p) {
      int col = p * 32 + bc;
      *reinterpret_cast<uint4*>(&Bh[col * APAD + bk]) =
          *reinterpret_cast<const uint4*>(&Wth[(size_t)col * N_FEAT + kc + bk]);
      *reinterpret_cast<uint4*>(&Bl[col * APAD + bk]) =
          *reinterpret_cast<const uint4*>(&Wtl[(size_t)col * N_FEAT + kc + bk]);
    }
#pragma unroll
    for (int p = 0; p < 8; ++p) {
      int nl = p * 16 + an;
      int gr = node0 + nl; if (gr > N_NODES - 1) gr = N_NODES - 1;
      const float4 v = *reinterpret_cast<const float4*>(&x[(size_t)gr * N_FEAT + kc + ak]);
      uint32_t u0 = __float_as_uint(v.x), u1 = __float_as_uint(v.y);
      uint32_t u2 = __float_as_uint(v.z), u3 = __float_as_uint(v.w);
      float f0 = v.x - __uint_as_float(u0 & 0xffff0000u);
      float f1 = v.y - __uint_as_float(u1 & 0xffff0000u);
      float f2 = v.z - __uint_as_float(u2 & 0xffff0000u);
      float f3 = v.w - __uint_as_float(u3 & 0xffff0000u);
      uint32_t hi01 = (u0 >> 16) | (u1 & 0xffff0000u);
      uint32_t hi23 = (u2 >> 16) | (u3 & 0xffff0000u);
      uint32_t lo01 = (__float_as_uint(f0) >> 16) | (__float_as_uint(f1) & 0xffff0000u);
      uint32_t lo23 = (__float_as_uint(f2) >> 16) | (__float_as_uint(f3) & 0xffff0000u);
      *reinterpret_cast<uint2*>(&Ah[nl * APAD + ak]) = make_uint2(hi01, hi23);
      *reinterpret_cast<uint2*>(&Al[nl * APAD + ak]) = make_uint2(lo01, lo23);
    }
    __syncthreads();
#pragma unroll
    for (int s = 0; s < 2; ++s) {
      int ko = s * 32 + l4 * 8;
      bf16x8 a_h[2], a_l[2], b_h[4], b_l[4];
#pragma unroll
      for (int r = 0; r < 2; ++r) {
        int row = w * 32 + r * 16 + l15;
        a_h[r] = *reinterpret_cast<const bf16x8*>(&Ah[row * APAD + ko]);
        a_l[r] = *reinterpret_cast<const bf16x8*>(&Al[row * APAD + ko]);
      }
#pragma unroll
      for (int c = 0; c < 4; ++c) {
        int col = c * 16 + l15;
        b_h[c] = *reinterpret_cast<const bf16x8*>(&Bh[col * APAD + ko]);
        b_l[c] = *reinterpret_cast<const bf16x8*>(&Bl[col * APAD + ko]);
      }
#pragma unroll
      for (int r = 0; r < 2; ++r)
#pragma unroll
        for (int c = 0; c < 4; ++c) {
          acc[r][c] = __builtin_amdgcn_mfma_f32_16x16x32_bf16(a_h[r], b_h[c], acc[r][c], 0, 0, 0);
          acc[r][c] = __builtin_amdgcn_mfma_f32_16x16x32_bf16(a_h[r], b_l[c], acc[r][c], 0, 0, 0);
          acc[r][c] = __builtin_amdgcn_mfma_f32_16x16x32_bf16(a_l[r], b_h[c], acc[r][c], 0, 0, 0);
        }
    }
    __syncthreads();
  }
  // epilogue: scale by dinv, pack bf16, transpose via LDS, dwordx4 stores
#pragma unroll
  for (int r = 0; r < 2; ++r)
#pragma unroll
    for (int q = 0; q < 4; ++q) {
      int nl = w * 32 + r * 16 + l4 * 4 + q;
      int node = node0 + nl;
      if (node < N_NODES) {
        float dv = dinv[node];
#pragma unroll
        for (int c = 0; c < 4; ++c)
          Ah[nl * APAD + c * 16 + l15] = f2bf(acc[r][c][q] * dv);
      }
    }
  __syncthreads();
#pragma unroll
  for (int p = 0; p < 4; ++p) {
    int row = p * 32 + (t >> 3);
    int seg = t & 7;
    int node = node0 + row;
    if (node < N_NODES) {
      uint4 v = *reinterpret_cast<const uint4*>(&Ah[row * APAD + seg * 8]);
      *reinterpret_cast<uint4*>(&hs1[(size_t)node * HIDDEN + seg * 8]) = v;
    }
  }
}

// ---- Fused layer-1 aggregation + ReLU + dropout + GEMM2 --------------------
// Pair-gather: lane = (edge-parity h, feature-pair q). Each lane loads one
// dword (2 bf16 feats) from its half's edge — per 8 edges: 4 gather loads +
// 4 srcs loads per lane (vs 8+8 with 2B loads), full 4B/lane coalescing.
// Halves merged via shfl_xor(32); redistributed to one-feat-per-lane for the
// epilogue (ReLU, dropout, fused gemm2 shfl-FMA).
__global__ __launch_bounds__(256) void agg1_kernel(const uint16_t* __restrict__ hs,
                                                   const int* __restrict__ rowstart,
                                                   const int* __restrict__ srcs,
                                                   const float* __restrict__ dinv,
                                                   const float* __restrict__ bias,
                                                   const float* __restrict__ W2,
                                                   uint16_t* __restrict__ gs) {
  __shared__ float w2s[HIDDEN * N_CLASSES + 64];  // +64 pad: lanes 40..63 OOB-safe
  int t = threadIdx.x;
  for (int i = t; i < HIDDEN * N_CLASSES; i += 256) w2s[i] = W2[i];
  __syncthreads();
  int wid = (blockIdx.x * 256 + t) >> 6;          // one wave per dst node
  int lane = t & 63;
  if (wid >= N_NODES) return;                     // wave-uniform; no sync below
  int h = lane >> 5;                              // edge-parity half
  int q2 = (lane & 31) * 2;                       // feature-pair base
  int beg = rowstart[wid], end = rowstart[wid + 1];
  float ax = 0.f, ay = 0.f;                       // even / odd feat partial sums
  int e = beg;
  for (; e + 8 <= end; e += 8) {                  // 4 edges per half in flight
    int s0 = srcs[e + h];
    int s1 = srcs[e + 2 + h];
    int s2 = srcs[e + 4 + h];
    int s3 = srcs[e + 6 + h];
    uint32_t a0 = *reinterpret_cast<const uint32_t*>(&hs[(size_t)s0 * HIDDEN + q2]);
    uint32_t a1 = *reinterpret_cast<const uint32_t*>(&hs[(size_t)s1 * HIDDEN + q2]);
    uint32_t a2 = *reinterpret_cast<const uint32_t*>(&hs[(size_t)s2 * HIDDEN + q2]);
    uint32_t a3 = *reinterpret_cast<const uint32_t*>(&hs[(size_t)s3 * HIDDEN + q2]);
    ax += (bflo(a0) + bflo(a1)) + (bflo(a2) + bflo(a3));
    ay += (bfhi(a0) + bfhi(a1)) + (bfhi(a2) + bfhi(a3));
  }
  for (; e + 2 <= end; e += 2) {                  // pair tail
    int s = srcs[e + h];
    uint32_t a = *reinterpret_cast<const uint32_t*>(&hs[(size_t)s * HIDDEN + q2]);
    ax += bflo(a); ay += bfhi(a);
  }
  if (e < end && h == 0) {                        // odd single edge: half 0 only
    int s = srcs[e];
    uint32_t a = *reinterpret_cast<const uint32_t*>(&hs[(size_t)s * HIDDEN + q2]);
    ax += bflo(a); ay += bfhi(a);
  }
  ax += __shfl_xor(ax, 32);                       // merge edge-parity halves
  ay += __shfl_xor(ay, 32);
  float vlo = __shfl(ax, lane >> 1);              // redistribute: feat per lane
  float vhi = __shfl(ay, lane >> 1);
  float v = (lane & 1) ? vhi : vlo;
  v += bf2f(hs[(size_t)wid * HIDDEN + lane]);     // self-loop term
  v = v * dinv[wid] + bias[lane];
  v = fmaxf(v, 0.f);
  // JAX dropout, jax_threefry_partitionable=True:
  // bits(i) = o0^o1 of threefry2x32(key=(0,42), (0,i)); drop iff bit31 set.
  uint32_t i = (uint32_t)wid * 64u + (uint32_t)lane;
  uint32_t o0, o1;
  threefry2x32(0u, 42u, 0u, i, o0, o1);
  v = ((o0 ^ o1) & 0x80000000u) ? 0.f : v * 2.f;
  // fused gemm2: gs[wid][lane] = (h1_row @ W2)[lane] * dinv[wid]
  float o = 0.f;
#pragma unroll 8
  for (int j = 0; j < HIDDEN; j++) {
    float hj = __shfl(v, j);
    o += hj * w2s[j * N_CLASSES + lane];
  }
  // gs padded to 64 cols so agg2 can use the same 128B-row pair gather
  gs[(size_t)wid * HIDDEN + lane] =
      (lane < N_CLASSES) ? f2bf(o * dinv[wid]) : (uint16_t)0;
}

// -------- Layer-2 pull aggregation (pair-gather over padded gs rows) --------
__global__ __launch_bounds__(256) void agg2_kernel(const uint16_t* __restrict__ gsp,
                                                   const int* __restrict__ rowstart,
                                                   const int* __restrict__ srcs,
                                                   const float* __restrict__ dinv,
                                                   const float* __restrict__ bias,
                                                   float* __restrict__ outp) {
  int t = threadIdx.x;
  int wid = (blockIdx.x * 256 + t) >> 6;          // one wave per dst node
  int lane = t & 63;
  if (wid >= N_NODES) return;
  int h = lane >> 5;
  int q2 = (lane & 31) * 2;
  int beg = rowstart[wid], end = rowstart[wid + 1];
  float ax = 0.f, ay = 0.f;
  int e = beg;
  for (; e + 8 <= end; e += 8) {
    int s0 = srcs[e + h];
    int s1 = srcs[e + 2 + h];
    int s2 = srcs[e + 4 + h];
    int s3 = srcs[e + 6 + h];
    uint32_t a0 = *reinterpret_cast<const uint32_t*>(&gsp[(size_t)s0 * HIDDEN + q2]);
    uint32_t a1 = *reinterpret_cast<const uint32_t*>(&gsp[(size_t)s1 * HIDDEN + q2]);
    uint32_t a2 = *reinterpret_cast<const uint32_t*>(&gsp[(size_t)s2 * HIDDEN + q2]);
    uint32_t a3 = *reinterpret_cast<const uint32_t*>(&gsp[(size_t)s3 * HIDDEN + q2]);
    ax += (bflo(a0) + bflo(a1)) + (bflo(a2) + bflo(a3));
    ay += (bfhi(a0) + bfhi(a1)) + (bfhi(a2) + bfhi(a3));
  }
  for (; e + 2 <= end; e += 2) {
    int s = srcs[e + h];
    uint32_t a = *reinterpret_cast<const uint32_t*>(&gsp[(size_t)s * HIDDEN + q2]);
    ax += bflo(a); ay += bfhi(a);
  }
  if (e < end && h == 0) {
    int s = srcs[e];
    uint32_t a = *reinterpret_cast<const uint32_t*>(&gsp[(size_t)s * HIDDEN + q2]);
    ax += bflo(a); ay += bfhi(a);
  }
  ax += __shfl_xor(ax, 32);
  ay += __shfl_xor(ay, 32);
  float vlo = __shfl(ax, lane >> 1);
  float vhi = __shfl(ay, lane >> 1);
  float v = (lane & 1) ? vhi : vlo;
  if (lane < N_CLASSES) {
    v += bf2f(gsp[(size_t)wid * HIDDEN + lane]);  // self-loop term
    outp[(size_t)wid * N_CLASSES + lane] = v * dinv[wid] + bias[lane];
  }
}

// ---------------- launch -----------------------------------------------------
extern "C" void kernel_launch(void* const* d_in, const int* in_sizes, int n_in,
                              void* d_out, int out_size, void* d_ws, size_t ws_size,
                              hipStream_t stream) {
  const float* x   = (const float*)d_in[0];
  const int* edges = (const int*)d_in[1];  // [2*E] int32: row0=src, row1=dst
  const float* W1  = (const float*)d_in[2];
  const float* b1  = (const float*)d_in[3];
  const float* W2  = (const float*)d_in[4];
  const float* b2  = (const float*)d_in[5];
  float* out = (float*)d_out;

  char* ws = (char*)d_ws;
  size_t off = 0;
  auto alloc = [&](size_t bytes) -> void* {
    void* p = ws + off;
    off = (off + bytes + 255) & ~(size_t)255;
    return p;
  };
  int*      rowstart = (int*)alloc((size_t)(N_NODES + 1) * 4);
  float*    dinv     = (float*)alloc((size_t)N_NODES * 4);
  int*      gcursor  = (int*)alloc(256 * 4);
  int*      bstart   = (int*)alloc(256 * 4);
  int*      srcs     = (int*)alloc((size_t)N_EDGES * 4);
  uint32_t* gbins    = (uint32_t*)alloc((size_t)NB * CAP * 4);
  uint16_t* hs1      = (uint16_t*)alloc((size_t)N_NODES * HIDDEN * 2);
  uint16_t* gs       = (uint16_t*)alloc((size_t)N_NODES * HIDDEN * 2);  // padded to 64
  uint16_t* Wth      = (uint16_t*)alloc((size_t)HIDDEN * N_FEAT * 2);
  uint16_t* Wtl      = (uint16_t*)alloc((size_t)HIDDEN * N_FEAT * 2);

  init_kernel<<<1, 256, 0, stream>>>(gcursor);
  wprep_kernel<<<(HIDDEN * N_FEAT) / 256, 256, 0, stream>>>(W1, Wth, Wtl);
  bin_kernel<<<(N_EDGES + CHUNK - 1) / CHUNK, 256, 0, stream>>>(edges, gcursor, gbins);
  sizes_scan<<<1, 256, 0, stream>>>(gcursor, bstart, rowstart);
  node_kernel<<<NB, 512, 0, stream>>>(gbins, bstart, rowstart, srcs, dinv);
  gemm1_kernel<<<(N_NODES + 127) / 128, 256, 0, stream>>>(x, Wth, Wtl, dinv, hs1);
  agg1_kernel<<<(N_NODES * 64 + 255) / 256, 256, 0, stream>>>(
      hs1, rowstart, srcs, dinv, b1, W2, gs);
  agg2_kernel<<<(N_NODES * 64 + 255) / 256, 256, 0, stream>>>(
      gs, rowstart, srcs, dinv, b2, out);
}